// Round 18
// baseline (108.422 us; speedup 1.0000x reference)
//
#include <hip/hip_runtime.h>
#include <hip/hip_bf16.h>

typedef __attribute__((ext_vector_type(8)))  short short8;   // 8 x bf16 (4 VGPR)
typedef __attribute__((ext_vector_type(4)))  float f32x4;
typedef __attribute__((ext_vector_type(16))) float f32x16;
typedef __attribute__((ext_vector_type(4)))  unsigned int u32x4;

#define LOG2E 1.4426950408889634f

static __device__ __forceinline__ unsigned short f2bf(float f) {
    union { float f; unsigned u; } v; v.f = f;
    unsigned r = v.u + 0x7fffu + ((v.u >> 16) & 1u);   // RNE
    return (unsigned short)(r >> 16);
}
static __device__ __forceinline__ unsigned cvt_pk_bf16(float lo, float hi) {
    unsigned r;
    asm("v_cvt_pk_bf16_f32 %0, %1, %2" : "=v"(r) : "v"(lo), "v"(hi));
    return r;
}
static __device__ __forceinline__ float exp2_hw(float x) {
    float r;
    asm("v_exp_f32 %0, %1" : "=v"(r) : "v"(x));        // D = 2^S0
    return r;
}
// async global->LDS DMA: LDS dest = uniform base + lane*16B; global src per-lane.
static __device__ __forceinline__ void gll16(const unsigned short* g, unsigned short* lds) {
    __builtin_amdgcn_global_load_lds(
        (const __attribute__((address_space(1))) unsigned int*)g,
        (__attribute__((address_space(3))) unsigned int*)lds, 16, 0, 0);
}

// ---------------------------------------------------------------------------
// Kernel 0: W -> fragment-ordered Wtf.  group g = ct*8+kk (ct 0..19, kk 0..7):
// Wtf[g*512 + l*8 + j] = W[kk*32 + (l>>4)*8 + j][ct*16 + (l&15)]
// ---------------------------------------------------------------------------
__global__ __launch_bounds__(64) void transpose_w(
    const float* __restrict__ Wq, const float* __restrict__ Wk,
    const float* __restrict__ Wv, unsigned short* __restrict__ Wtf)
{
    const int g  = blockIdx.x;          // 0..159
    const int ct = g >> 3, kk = g & 7;
    const int l  = threadIdx.x;
    const int col = ct * 16 + (l & 15); // 0..319
    const int k0  = kk * 32 + (l >> 4) * 8;
    const float* W; int c, ldw;
    if (col < 32)      { W = Wq; c = col;      ldw = 32;  }
    else if (col < 64) { W = Wk; c = col - 32; ldw = 32;  }
    else               { W = Wv; c = col - 64; ldw = 256; }
    ushort4 o0, o1;
    o0.x = f2bf(W[(size_t)(k0 + 0) * ldw + c]);
    o0.y = f2bf(W[(size_t)(k0 + 1) * ldw + c]);
    o0.z = f2bf(W[(size_t)(k0 + 2) * ldw + c]);
    o0.w = f2bf(W[(size_t)(k0 + 3) * ldw + c]);
    o1.x = f2bf(W[(size_t)(k0 + 4) * ldw + c]);
    o1.y = f2bf(W[(size_t)(k0 + 5) * ldw + c]);
    o1.z = f2bf(W[(size_t)(k0 + 6) * ldw + c]);
    o1.w = f2bf(W[(size_t)(k0 + 7) * ldw + c]);
    *reinterpret_cast<ushort4*>(Wtf + (size_t)g * 512 + l * 8)     = o0;
    *reinterpret_cast<ushort4*>(Wtf + (size_t)g * 512 + l * 8 + 4) = o1;
}

// ---------------------------------------------------------------------------
// Kernel 1: QKV projection -> fragment-ordered Qb/Kf/Vf (layouts as r5).
// Grid 512 x 256: blockIdx>>1 = 64-token tile, blockIdx&1 = ct half.
// ---------------------------------------------------------------------------
__global__ __launch_bounds__(256) void proj_kernel(
    const float* __restrict__ x, const unsigned short* __restrict__ Wtf,
    const float* __restrict__ bq, const float* __restrict__ bk,
    const float* __restrict__ bv,
    unsigned short* __restrict__ Qb, unsigned short* __restrict__ Kf,
    unsigned short* __restrict__ Vf)
{
    __shared__ unsigned short x_lds[64][264];
    const int tid = threadIdx.x;
    const int M0  = (blockIdx.x >> 1) * 64;
    const int ctb = (blockIdx.x & 1) * 10;

    #pragma unroll
    for (int j = 0; j < 16; ++j) {
        int idx = j * 256 + tid;
        int row = idx >> 6;
        int qc  = idx & 63;
        const float4 v = *reinterpret_cast<const float4*>(x + (size_t)(M0 + row) * 256 + qc * 4);
        ushort4 o;
        o.x = f2bf(v.x); o.y = f2bf(v.y); o.z = f2bf(v.z); o.w = f2bf(v.w);
        *reinterpret_cast<ushort4*>(&x_lds[row][qc * 4]) = o;
    }
    __syncthreads();

    const int w  = tid >> 6;
    const int l  = tid & 63;
    const int lr = l & 15;
    const int lg = l >> 4;

    short8 a[8];
    #pragma unroll
    for (int kk = 0; kk < 8; ++kk)
        a[kk] = *reinterpret_cast<const short8*>(&x_lds[w * 16 + lr][kk * 32 + lg * 8]);

    const int b   = M0 >> 12;          // batch
    const int kt  = (M0 & 4095) >> 6;  // 64-token tile within batch

    for (int ct = ctb; ct < ctb + 10; ++ct) {
        const int col = ct * 16 + lr;           // 0..319
        f32x4 acc = {0.f, 0.f, 0.f, 0.f};
        #pragma unroll
        for (int kk = 0; kk < 8; ++kk) {
            const short8 bfr = *reinterpret_cast<const short8*>(
                Wtf + ((size_t)ct * 8 + kk) * 512 + l * 8);
            acc = __builtin_amdgcn_mfma_f32_16x16x32_bf16(a[kk], bfr, acc, 0, 0, 0);
        }
        const int rbase = M0 + w * 16 + lg * 4;        // global token of reg 0
        if (ct < 2) {           // Q, pre-scaled by log2e
            const float bias = bq[col];
            #pragma unroll
            for (int r = 0; r < 4; ++r)
                Qb[(size_t)(rbase + r) * 32 + col] = f2bf((acc[r] + bias) * LOG2E);
        } else if (ct < 4) {    // K -> fragment layout
            const int colp = col - 32;
            const float bias = bk[colp];
            const int dd = colp >> 4, hj = (colp >> 3) & 1, jj = colp & 7;
            #pragma unroll
            for (int r = 0; r < 4; ++r) {
                const int tt = (rbase + r) & 4095;
                const size_t e = (size_t)b * 131072 + (size_t)kt * 2048
                               + (((tt >> 5) & 1) * 2 + dd) * 512
                               + (hj * 32 + (tt & 31)) * 8 + jj;
                Kf[e] = f2bf(acc[r] + bias);
            }
        } else {                // V -> fragment layout (one 8B write)
            const int colp = col - 64;
            const float bias = bv[colp];
            const int kk_f = w;
            const int hi_v = (lg >> 1) & 1;
            const int j0   = (lg & 1) * 4;
            const size_t e = (size_t)b * 1048576 + (size_t)kt * 16384
                           + (colp >> 5) * 2048 + kk_f * 512
                           + (hi_v * 32 + (colp & 31)) * 8 + j0;
            ushort4 o;
            o.x = f2bf(acc[0] + bias); o.y = f2bf(acc[1] + bias);
            o.z = f2bf(acc[2] + bias); o.w = f2bf(acc[3] + bias);
            *reinterpret_cast<ushort4*>(Vf + e) = o;
        }
    }
}

// ---------------------------------------------------------------------------
// Kernel 2: flash attention — r17 tiling/math, T4 load discipline:
// all in-loop loads via global_load_lds into a wave-PRIVATE 10KB LDS slot
// (double-buffered), counted inline-asm vmcnt(10) so the next body's loads
// stay in flight across the whole current body (~1500 cy cover, enforced).
// No barriers in hot loop (private buffers). Bodies = 32k (64 per wave).
// Grid 1024 x 128 (2 independent kh waves); O_sh/l_sh reuse the pool.
// ---------------------------------------------------------------------------
__global__ __launch_bounds__(128, 2) void attn_kernel(
    const unsigned short* __restrict__ Qb, const unsigned short* __restrict__ Kf,
    const unsigned short* __restrict__ Vf, const float* __restrict__ x,
    const float* __restrict__ gamma_p, float* __restrict__ out)
{
    __shared__ short8 pool8[2560];     // 40960 B exactly: 2 waves x 2 parity x 10KB
    unsigned short* pool = (unsigned short*)pool8;

    const int i  = blockIdx.x;
    const int b  = (i & 7) >> 1;                    // batch -> XCD pair
    const int t  = ((i >> 3) << 1) | (i & 1);       // 0..255
    const int qt = t >> 1;                          // 0..127
    const int cg = t & 1;                           // col half

    const int tid = threadIdx.x;
    const int kh  = tid >> 6;                       // K-half wave
    const int l   = tid & 63;
    const int l5  = l & 31;
    const int hi  = l >> 5;

    const size_t bN = (size_t)b * 4096;
    const int q0 = qt * 32;
    const int c0 = cg * 128;

    // per-wave private LDS: parity slots of 5120 ushorts (10KB):
    //   V at (cgl*2+kkl)*512, K at 4096 + dd*512
    unsigned short* myBuf[2] = { pool + kh * 10240, pool + kh * 10240 + 5120 };

    const unsigned short* Kfb = Kf + (size_t)b * 131072 + l * 8;
    const unsigned short* Vfb = Vf + (size_t)b * 1048576 + (size_t)(c0 >> 5) * 2048 + l * 8;

    // Q B-frags (pre-scaled by log2e in proj)
    short8 qb[2];
    #pragma unroll
    for (int dd = 0; dd < 2; ++dd)
        qb[dd] = *reinterpret_cast<const short8*>(
            Qb + (bN + (size_t)(q0 + l5)) * 32 + dd * 16 + hi * 8);

    f32x16 Oa[4];
    #pragma unroll
    for (int ct = 0; ct < 4; ++ct)
        #pragma unroll
        for (int r = 0; r < 16; ++r) Oa[ct][r] = 0.f;
    float ls0 = 0.f, ls1 = 0.f, ls2 = 0.f, ls3 = 0.f;

    f32x16 z;
    #pragma unroll
    for (int r = 0; r < 16; ++r) z[r] = 0.f;

    // stage body bi (0..63 in this wave's K-half) into parity slot: 10 DMAs
    auto stage = [&](int bi, int parity) {
        const int g64   = kh * 32 + (bi >> 1);      // global 64-token tile
        const int khalf = bi & 1;                   // 32k half within it
        const unsigned short* vsrc = Vfb + (size_t)g64 * 16384 + khalf * 1024;
        unsigned short* dstb = myBuf[parity];
        #pragma unroll
        for (int cgl = 0; cgl < 4; ++cgl)
            #pragma unroll
            for (int kkl = 0; kkl < 2; ++kkl)
                gll16(vsrc + cgl * 2048 + kkl * 512, dstb + (cgl * 2 + kkl) * 512);
        const unsigned short* ksrc = Kfb + (size_t)g64 * 2048 + khalf * 1024;
        gll16(ksrc,       dstb + 4096);
        gll16(ksrc + 512, dstb + 4096 + 512);
    };

    stage(0, 0);                                    // prologue: 10 outstanding
    for (int bi = 0; bi < 64; ++bi) {
        stage((bi + 1) & 63, (bi + 1) & 1);         // +10 -> 20 outstanding
        asm volatile("s_waitcnt vmcnt(10)" ::: "memory");   // body bi's 10 landed
        __builtin_amdgcn_sched_barrier(0);          // rule #18: no hoisting above
        unsigned short* buf = myBuf[bi & 1];

        // K fragments (ds_read_b128, conflict-free linear)
        const short8 kA0 = *reinterpret_cast<const short8*>(buf + 4096 + l * 8);
        const short8 kA1 = *reinterpret_cast<const short8*>(buf + 4096 + 512 + l * 8);
        // swapped QK^T: p lane holds P[q=l5][k_local=(r&3)+8(r>>2)+4hi]
        f32x16 p = __builtin_amdgcn_mfma_f32_32x32x16_bf16(kA0, qb[0], z, 0, 0, 0);
        p        = __builtin_amdgcn_mfma_f32_32x32x16_bf16(kA1, qb[1], p, 0, 0, 0);
        // exp2 + rowsum (4 chains) + pack + permlane -> pa[2]
        short8 pa[2];
        {
            float e[16];
            #pragma unroll
            for (int r = 0; r < 16; ++r) {
                e[r] = exp2_hw(p[r]);
                switch (r & 3) {
                    case 0: ls0 += e[r]; break;
                    case 1: ls1 += e[r]; break;
                    case 2: ls2 += e[r]; break;
                    default: ls3 += e[r]; break;
                }
            }
            unsigned c[8];
            #pragma unroll
            for (int n = 0; n < 8; ++n) c[n] = cvt_pk_bf16(e[2 * n], e[2 * n + 1]);
            #pragma unroll
            for (int k2 = 0; k2 < 2; ++k2) {
                unsigned d0 = c[4 * k2 + 0], d2 = c[4 * k2 + 2];
                unsigned d1 = c[4 * k2 + 1], d3 = c[4 * k2 + 3];
                asm("v_permlane32_swap_b32 %0, %1" : "+v"(d0), "+v"(d2));
                asm("v_permlane32_swap_b32 %0, %1" : "+v"(d1), "+v"(d3));
                u32x4 u = {d0, d1, d2, d3};
                pa[k2] = __builtin_bit_cast(short8, u);
            }
        }
        // PV: 4 col-subtiles x 2 k-frags from LDS (kk-outer for acc distance)
        #pragma unroll
        for (int kk = 0; kk < 2; ++kk)
            #pragma unroll
            for (int ct = 0; ct < 4; ++ct) {
                const short8 vf = *reinterpret_cast<const short8*>(
                    buf + (ct * 2 + kk) * 512 + l * 8);
                Oa[ct] = __builtin_amdgcn_mfma_f32_32x32x16_bf16(pa[kk], vf, Oa[ct], 0, 0, 0);
            }
    }

    // ---- combine: reuse pool as O_sh/l_sh after the loop ----
    float lsum = (ls0 + ls1) + (ls2 + ls3);
    lsum += __shfl_xor(lsum, 32);
    __syncthreads();                                // retire stage buffers
    float* O_shf = (float*)pool;                    // [4][16][64] = 16KB
    float* l_shf = (float*)pool + 4096;             // [2][32]
    if (hi == 0) l_shf[kh * 32 + l5] = lsum;
    #pragma unroll
    for (int ct = 0; ct < 4; ++ct)
        if ((ct >> 1) != kh) {
            #pragma unroll
            for (int r = 0; r < 16; ++r)
                O_shf[(ct * 16 + r) * 64 + hi * 32 + l5] = Oa[ct][r];
        }
    __syncthreads();

    const float gamma = gamma_p[0];
    #pragma unroll
    for (int ct = 0; ct < 4; ++ct)
        if ((ct >> 1) == kh) {
            #pragma unroll
            for (int r = 0; r < 16; ++r) {
                const int qr = (r & 3) + 8 * (r >> 2) + 4 * hi;
                const float ltot = l_shf[qr] + l_shf[32 + qr];
                const float osum = Oa[ct][r] + O_shf[(ct * 16 + r) * 64 + hi * 32 + l5];
                const size_t idx = (bN + (size_t)(q0 + qr)) * 256 + c0 + ct * 32 + l5;
                out[idx] = gamma * (osum / ltot) + x[idx];
            }
        }
}

// ---------------------------------------------------------------------------
extern "C" void kernel_launch(void* const* d_in, const int* in_sizes, int n_in,
                              void* d_out, int out_size, void* d_ws, size_t ws_size,
                              hipStream_t stream) {
    const float* x     = (const float*)d_in[0];
    const float* Wq    = (const float*)d_in[1];
    const float* bq    = (const float*)d_in[2];
    const float* Wk    = (const float*)d_in[3];
    const float* bk    = (const float*)d_in[4];
    const float* Wv    = (const float*)d_in[5];
    const float* bv    = (const float*)d_in[6];
    const float* gamma = (const float*)d_in[7];
    float* out = (float*)d_out;

    // workspace: Qb 1MB | Kf 1MB | Vf 8MB | Wtf 160KB (bf16)
    unsigned short* Qb  = (unsigned short*)d_ws;
    unsigned short* Kf  = Qb + (size_t)16384 * 32;
    unsigned short* Vf  = Kf + (size_t)16384 * 32;
    unsigned short* Wtf = Vf + (size_t)4 * 256 * 4096;

    transpose_w<<<160, 64, 0, stream>>>(Wq, Wk, Wv, Wtf);
    proj_kernel<<<512, 256, 0, stream>>>(x, Wtf, bq, bk, bv, Qb, Kf, Vf);
    attn_kernel<<<1024, 128, 0, stream>>>(Qb, Kf, Vf, x, gamma, out);
}

// Round 19
// 86.484 us; speedup vs baseline: 1.2537x; 1.2537x over previous
//
#include <hip/hip_runtime.h>
#include <hip/hip_bf16.h>

typedef __attribute__((ext_vector_type(8)))  short short8;   // 8 x bf16 (4 VGPR)
typedef __attribute__((ext_vector_type(4)))  float f32x4;
typedef __attribute__((ext_vector_type(16))) float f32x16;
typedef __attribute__((ext_vector_type(4)))  unsigned int u32x4;

#define LOG2E 1.4426950408889634f

static __device__ __forceinline__ unsigned short f2bf(float f) {
    union { float f; unsigned u; } v; v.f = f;
    unsigned r = v.u + 0x7fffu + ((v.u >> 16) & 1u);   // RNE
    return (unsigned short)(r >> 16);
}
static __device__ __forceinline__ unsigned cvt_pk_bf16(float lo, float hi) {
    unsigned r;
    asm("v_cvt_pk_bf16_f32 %0, %1, %2" : "=v"(r) : "v"(lo), "v"(hi));
    return r;
}
static __device__ __forceinline__ float exp2_hw(float x) {
    float r;
    asm("v_exp_f32 %0, %1" : "=v"(r) : "v"(x));        // D = 2^S0
    return r;
}

// ---------------------------------------------------------------------------
// Kernel 0: W -> fragment-ordered Wtf.  group g = ct*8+kk (ct 0..19, kk 0..7):
// Wtf[g*512 + l*8 + j] = W[kk*32 + (l>>4)*8 + j][ct*16 + (l&15)]
// ---------------------------------------------------------------------------
__global__ __launch_bounds__(64) void transpose_w(
    const float* __restrict__ Wq, const float* __restrict__ Wk,
    const float* __restrict__ Wv, unsigned short* __restrict__ Wtf)
{
    const int g  = blockIdx.x;          // 0..159
    const int ct = g >> 3, kk = g & 7;
    const int l  = threadIdx.x;
    const int col = ct * 16 + (l & 15); // 0..319
    const int k0  = kk * 32 + (l >> 4) * 8;
    const float* W; int c, ldw;
    if (col < 32)      { W = Wq; c = col;      ldw = 32;  }
    else if (col < 64) { W = Wk; c = col - 32; ldw = 32;  }
    else               { W = Wv; c = col - 64; ldw = 256; }
    ushort4 o0, o1;
    o0.x = f2bf(W[(size_t)(k0 + 0) * ldw + c]);
    o0.y = f2bf(W[(size_t)(k0 + 1) * ldw + c]);
    o0.z = f2bf(W[(size_t)(k0 + 2) * ldw + c]);
    o0.w = f2bf(W[(size_t)(k0 + 3) * ldw + c]);
    o1.x = f2bf(W[(size_t)(k0 + 4) * ldw + c]);
    o1.y = f2bf(W[(size_t)(k0 + 5) * ldw + c]);
    o1.z = f2bf(W[(size_t)(k0 + 6) * ldw + c]);
    o1.w = f2bf(W[(size_t)(k0 + 7) * ldw + c]);
    *reinterpret_cast<ushort4*>(Wtf + (size_t)g * 512 + l * 8)     = o0;
    *reinterpret_cast<ushort4*>(Wtf + (size_t)g * 512 + l * 8 + 4) = o1;
}

// ---------------------------------------------------------------------------
// Kernel 1: QKV projection -> fragment-ordered Qb/Kf/Vf (layouts as r5).
// Grid 256 x 256: one block per 64-token tile, ALL 20 cts (x staged ONCE —
// r4's 512-block ct-split staged every x tile twice = +16MB HBM reads).
// ---------------------------------------------------------------------------
__global__ __launch_bounds__(256) void proj_kernel(
    const float* __restrict__ x, const unsigned short* __restrict__ Wtf,
    const float* __restrict__ bq, const float* __restrict__ bk,
    const float* __restrict__ bv,
    unsigned short* __restrict__ Qb, unsigned short* __restrict__ Kf,
    unsigned short* __restrict__ Vf)
{
    __shared__ unsigned short x_lds[64][264];
    const int tid = threadIdx.x;
    const int M0  = blockIdx.x * 64;

    #pragma unroll
    for (int j = 0; j < 16; ++j) {
        int idx = j * 256 + tid;
        int row = idx >> 6;
        int qc  = idx & 63;
        const float4 v = *reinterpret_cast<const float4*>(x + (size_t)(M0 + row) * 256 + qc * 4);
        ushort4 o;
        o.x = f2bf(v.x); o.y = f2bf(v.y); o.z = f2bf(v.z); o.w = f2bf(v.w);
        *reinterpret_cast<ushort4*>(&x_lds[row][qc * 4]) = o;
    }
    __syncthreads();

    const int w  = tid >> 6;
    const int l  = tid & 63;
    const int lr = l & 15;
    const int lg = l >> 4;

    short8 a[8];
    #pragma unroll
    for (int kk = 0; kk < 8; ++kk)
        a[kk] = *reinterpret_cast<const short8*>(&x_lds[w * 16 + lr][kk * 32 + lg * 8]);

    const int b   = M0 >> 12;          // batch
    const int kt  = (M0 & 4095) >> 6;  // 64-token tile within batch

    for (int ct = 0; ct < 20; ++ct) {
        const int col = ct * 16 + lr;           // 0..319
        f32x4 acc = {0.f, 0.f, 0.f, 0.f};
        #pragma unroll
        for (int kk = 0; kk < 8; ++kk) {
            const short8 bfr = *reinterpret_cast<const short8*>(
                Wtf + ((size_t)ct * 8 + kk) * 512 + l * 8);
            acc = __builtin_amdgcn_mfma_f32_16x16x32_bf16(a[kk], bfr, acc, 0, 0, 0);
        }
        const int rbase = M0 + w * 16 + lg * 4;        // global token of reg 0
        if (ct < 2) {           // Q, pre-scaled by log2e
            const float bias = bq[col];
            #pragma unroll
            for (int r = 0; r < 4; ++r)
                Qb[(size_t)(rbase + r) * 32 + col] = f2bf((acc[r] + bias) * LOG2E);
        } else if (ct < 4) {    // K -> fragment layout
            const int colp = col - 32;
            const float bias = bk[colp];
            const int dd = colp >> 4, hj = (colp >> 3) & 1, jj = colp & 7;
            #pragma unroll
            for (int r = 0; r < 4; ++r) {
                const int tt = (rbase + r) & 4095;
                const size_t e = (size_t)b * 131072 + (size_t)kt * 2048
                               + (((tt >> 5) & 1) * 2 + dd) * 512
                               + (hj * 32 + (tt & 31)) * 8 + jj;
                Kf[e] = f2bf(acc[r] + bias);
            }
        } else {                // V -> fragment layout (one 8B write)
            const int colp = col - 64;
            const float bias = bv[colp];
            const int kk_f = w;
            const int hi_v = (lg >> 1) & 1;
            const int j0   = (lg & 1) * 4;
            const size_t e = (size_t)b * 1048576 + (size_t)kt * 16384
                           + (colp >> 5) * 2048 + kk_f * 512
                           + (hi_v * 32 + (colp & 31)) * 8 + j0;
            ushort4 o;
            o.x = f2bf(acc[0] + bias); o.y = f2bf(acc[1] + bias);
            o.z = f2bf(acc[2] + bias); o.w = f2bf(acc[3] + bias);
            *reinterpret_cast<ushort4*>(Vf + e) = o;
        }
    }
}

// ---------------------------------------------------------------------------
// Kernel 2: flash attention — r17 VERBATIM (best measured: 58.1 µs).
// Register softmax, fragment-linear K/V loads, cross-body V + kA double-
// buffers, ILP-shaped (PV kk-outer, QK interleaved, 4 rowsum chains),
// VALU rowsum, NO setprio (r12: -25%), NO LDS staging (r18: -64%).
// Grid 1024 x 128 (2 independent kh waves).
// ---------------------------------------------------------------------------
__global__ __launch_bounds__(128, 2) void attn_kernel(
    const unsigned short* __restrict__ Qb, const unsigned short* __restrict__ Kf,
    const unsigned short* __restrict__ Vf, const float* __restrict__ x,
    const float* __restrict__ gamma_p, float* __restrict__ out)
{
    __shared__ float O_sh[4][16][64];   // partner partials, 16KB
    __shared__ float l_sh[2][32];

    const int i  = blockIdx.x;
    const int b  = (i & 7) >> 1;                    // batch -> XCD pair
    const int t  = ((i >> 3) << 1) | (i & 1);       // 0..255
    const int qt = t >> 1;                          // 0..127
    const int cg = t & 1;                           // col half

    const int tid = threadIdx.x;
    const int kh  = tid >> 6;                       // K-half wave
    const int l   = tid & 63;
    const int l5  = l & 31;
    const int hi  = l >> 5;

    const size_t bN = (size_t)b * 4096;
    const int q0 = qt * 32;
    const int c0 = cg * 128;

    // fragment bases (lane offset folded in)
    const unsigned short* Kfb = Kf + (size_t)b * 131072 + l * 8;
    const unsigned short* Vfb = Vf + (size_t)b * 1048576 + (c0 >> 5) * 2048 + l * 8;

    // Q B-frags (pre-scaled by log2e in proj)
    short8 qb[2];
    #pragma unroll
    for (int dd = 0; dd < 2; ++dd)
        qb[dd] = *reinterpret_cast<const short8*>(
            Qb + (bN + (size_t)(q0 + l5)) * 32 + dd * 16 + hi * 8);

    f32x16 Oa[4];
    #pragma unroll
    for (int ct = 0; ct < 4; ++ct)
        #pragma unroll
        for (int r = 0; r < 16; ++r) Oa[ct][r] = 0.f;
    float ls0 = 0.f, ls1 = 0.f, ls2 = 0.f, ls3 = 0.f;   // 4 chains of 8/body

    f32x16 z;
    #pragma unroll
    for (int r = 0; r < 16; ++r) z[r] = 0.f;

    const int kt0 = kh * 32;                        // wave's first 64-token tile

    auto loadK = [&](short8 (&kA)[2][2], int ktg) {
        const unsigned short* kp = Kfb + (size_t)ktg * 2048;
        #pragma unroll
        for (int ks = 0; ks < 2; ++ks)
            #pragma unroll
            for (int dd = 0; dd < 2; ++dd)
                kA[ks][dd] = *reinterpret_cast<const short8*>(kp + (ks * 2 + dd) * 512);
    };
    auto loadV = [&](short8 (&vA)[4][4], int ktg) {
        const unsigned short* vp = Vfb + (size_t)ktg * 16384;
        #pragma unroll
        for (int ct = 0; ct < 4; ++ct)
            #pragma unroll
            for (int kk = 0; kk < 4; ++kk)
                vA[ct][kk] = *reinterpret_cast<const short8*>(vp + ct * 2048 + kk * 512);
    };

    // body: prefetch NEXT body's V and K first; compute with current buffers.
    auto body = [&](short8 (&kcur)[2][2], short8 (&knxt)[2][2],
                    short8 (&vcur)[4][4], short8 (&vnxt)[4][4], int ktgn) {
        loadV(vnxt, ktgn);                          // full-body latency cover
        loadK(knxt, ktgn);
        // swapped QK^T, p0/p1 interleaved (independent chains, distance 2)
        f32x16 p0 = __builtin_amdgcn_mfma_f32_32x32x16_bf16(kcur[0][0], qb[0], z, 0, 0, 0);
        f32x16 p1 = __builtin_amdgcn_mfma_f32_32x32x16_bf16(kcur[1][0], qb[0], z, 0, 0, 0);
        p0        = __builtin_amdgcn_mfma_f32_32x32x16_bf16(kcur[0][1], qb[1], p0, 0, 0, 0);
        p1        = __builtin_amdgcn_mfma_f32_32x32x16_bf16(kcur[1][1], qb[1], p1, 0, 0, 0);
        // exp2 + rowsum (4 chains) + pack + permlane -> PV A-frags
        short8 pa[4];
        #pragma unroll
        for (int ks = 0; ks < 2; ++ks) {
            float e[16];
            #pragma unroll
            for (int r = 0; r < 16; ++r) {
                const float s = (ks == 0) ? p0[r] : p1[r];
                e[r] = exp2_hw(s);
                switch (r & 3) {
                    case 0: ls0 += e[r]; break;
                    case 1: ls1 += e[r]; break;
                    case 2: ls2 += e[r]; break;
                    default: ls3 += e[r]; break;
                }
            }
            unsigned c[8];
            #pragma unroll
            for (int n = 0; n < 8; ++n) c[n] = cvt_pk_bf16(e[2 * n], e[2 * n + 1]);
            #pragma unroll
            for (int k2 = 0; k2 < 2; ++k2) {
                unsigned d0 = c[4 * k2 + 0], d2 = c[4 * k2 + 2];
                unsigned d1 = c[4 * k2 + 1], d3 = c[4 * k2 + 3];
                asm("v_permlane32_swap_b32 %0, %1" : "+v"(d0), "+v"(d2));
                asm("v_permlane32_swap_b32 %0, %1" : "+v"(d1), "+v"(d3));
                u32x4 u = {d0, d1, d2, d3};
                pa[ks * 2 + k2] = __builtin_bit_cast(short8, u);
            }
        }
        // PV: kk-outer -> same-accumulator MFMAs are 4 apart (indep chains)
        #pragma unroll
        for (int kk = 0; kk < 4; ++kk)
            #pragma unroll
            for (int ct = 0; ct < 4; ++ct)
                Oa[ct] = __builtin_amdgcn_mfma_f32_32x32x16_bf16(pa[kk], vcur[ct][kk], Oa[ct], 0, 0, 0);
    };

    short8 kA0[2][2], kA1[2][2];
    short8 vA[4][4], vB[4][4];
    loadK(kA0, kt0);
    loadV(vA, kt0);
    for (int kt = 0; kt < 32; kt += 2) {
        body(kA0, kA1, vA, vB, kt0 + kt + 1);
        body(kA1, kA0, vB, vA, kt0 + ((kt + 2) & 31));   // last prefetch wraps
    }

    // ---- combine: rowsum across hi halves; partner O partials via LDS ----
    float lsum = (ls0 + ls1) + (ls2 + ls3);
    lsum += __shfl_xor(lsum, 32);
    if (hi == 0) l_sh[kh][l5] = lsum;
    #pragma unroll
    for (int ct = 0; ct < 4; ++ct)
        if ((ct >> 1) != kh) {
            #pragma unroll
            for (int r = 0; r < 16; ++r)
                O_sh[ct][r][hi * 32 + l5] = Oa[ct][r];
        }
    __syncthreads();

    const float gamma = gamma_p[0];
    #pragma unroll
    for (int ct = 0; ct < 4; ++ct)
        if ((ct >> 1) == kh) {
            #pragma unroll
            for (int r = 0; r < 16; ++r) {
                const int qr = (r & 3) + 8 * (r >> 2) + 4 * hi;
                const float ltot = l_sh[0][qr] + l_sh[1][qr];
                const float osum = Oa[ct][r] + O_sh[ct][r][hi * 32 + l5];
                const size_t idx = (bN + (size_t)(q0 + qr)) * 256 + c0 + ct * 32 + l5;
                out[idx] = gamma * (osum / ltot) + x[idx];
            }
        }
}

// ---------------------------------------------------------------------------
extern "C" void kernel_launch(void* const* d_in, const int* in_sizes, int n_in,
                              void* d_out, int out_size, void* d_ws, size_t ws_size,
                              hipStream_t stream) {
    const float* x     = (const float*)d_in[0];
    const float* Wq    = (const float*)d_in[1];
    const float* bq    = (const float*)d_in[2];
    const float* Wk    = (const float*)d_in[3];
    const float* bk    = (const float*)d_in[4];
    const float* Wv    = (const float*)d_in[5];
    const float* bv    = (const float*)d_in[6];
    const float* gamma = (const float*)d_in[7];
    float* out = (float*)d_out;

    // workspace: Qb 1MB | Kf 1MB | Vf 8MB | Wtf 160KB (bf16)
    unsigned short* Qb  = (unsigned short*)d_ws;
    unsigned short* Kf  = Qb + (size_t)16384 * 32;
    unsigned short* Vf  = Kf + (size_t)16384 * 32;
    unsigned short* Wtf = Vf + (size_t)4 * 256 * 4096;

    transpose_w<<<160, 64, 0, stream>>>(Wq, Wk, Wv, Wtf);
    proj_kernel<<<256, 256, 0, stream>>>(x, Wtf, bq, bk, bv, Qb, Kf, Vf);
    attn_kernel<<<1024, 128, 0, stream>>>(Qb, Kf, Vf, x, gamma, out);
}

// Round 20
// 79.779 us; speedup vs baseline: 1.3590x; 1.0840x over previous
//
#include <hip/hip_runtime.h>
#include <hip/hip_bf16.h>

typedef __attribute__((ext_vector_type(8)))  short short8;   // 8 x bf16 (4 VGPR)
typedef __attribute__((ext_vector_type(4)))  float f32x4;
typedef __attribute__((ext_vector_type(16))) float f32x16;
typedef __attribute__((ext_vector_type(4)))  unsigned int u32x4;

#define LOG2E 1.4426950408889634f

static __device__ __forceinline__ unsigned short f2bf(float f) {
    union { float f; unsigned u; } v; v.f = f;
    unsigned r = v.u + 0x7fffu + ((v.u >> 16) & 1u);   // RNE
    return (unsigned short)(r >> 16);
}
static __device__ __forceinline__ unsigned cvt_pk_bf16(float lo, float hi) {
    unsigned r;
    asm("v_cvt_pk_bf16_f32 %0, %1, %2" : "=v"(r) : "v"(lo), "v"(hi));
    return r;
}
static __device__ __forceinline__ float exp2_hw(float x) {
    float r;
    asm("v_exp_f32 %0, %1" : "=v"(r) : "v"(x));        // D = 2^S0
    return r;
}

// ---------------------------------------------------------------------------
// Kernel 0: W -> fragment-ordered Wtf.  group g = ct*8+kk (ct 0..19, kk 0..7):
// Wtf[g*512 + l*8 + j] = W[kk*32 + (l>>4)*8 + j][ct*16 + (l&15)]
// ---------------------------------------------------------------------------
__global__ __launch_bounds__(64) void transpose_w(
    const float* __restrict__ Wq, const float* __restrict__ Wk,
    const float* __restrict__ Wv, unsigned short* __restrict__ Wtf)
{
    const int g  = blockIdx.x;          // 0..159
    const int ct = g >> 3, kk = g & 7;
    const int l  = threadIdx.x;
    const int col = ct * 16 + (l & 15); // 0..319
    const int k0  = kk * 32 + (l >> 4) * 8;
    const float* W; int c, ldw;
    if (col < 32)      { W = Wq; c = col;      ldw = 32;  }
    else if (col < 64) { W = Wk; c = col - 32; ldw = 32;  }
    else               { W = Wv; c = col - 64; ldw = 256; }
    ushort4 o0, o1;
    o0.x = f2bf(W[(size_t)(k0 + 0) * ldw + c]);
    o0.y = f2bf(W[(size_t)(k0 + 1) * ldw + c]);
    o0.z = f2bf(W[(size_t)(k0 + 2) * ldw + c]);
    o0.w = f2bf(W[(size_t)(k0 + 3) * ldw + c]);
    o1.x = f2bf(W[(size_t)(k0 + 4) * ldw + c]);
    o1.y = f2bf(W[(size_t)(k0 + 5) * ldw + c]);
    o1.z = f2bf(W[(size_t)(k0 + 6) * ldw + c]);
    o1.w = f2bf(W[(size_t)(k0 + 7) * ldw + c]);
    *reinterpret_cast<ushort4*>(Wtf + (size_t)g * 512 + l * 8)     = o0;
    *reinterpret_cast<ushort4*>(Wtf + (size_t)g * 512 + l * 8 + 4) = o1;
}

// ---------------------------------------------------------------------------
// Kernel 1: QKV projection -> fragment-ordered Qb/Kf/Vf (layouts as r5).
// Grid 512 x 256: blockIdx>>1 = 64-token tile, blockIdx&1 = ct half.
// (2 blocks/CU = 2 waves/SIMD; r19's 256-block 1-wave/SIMD variant was -6µs.)
// ---------------------------------------------------------------------------
__global__ __launch_bounds__(256) void proj_kernel(
    const float* __restrict__ x, const unsigned short* __restrict__ Wtf,
    const float* __restrict__ bq, const float* __restrict__ bk,
    const float* __restrict__ bv,
    unsigned short* __restrict__ Qb, unsigned short* __restrict__ Kf,
    unsigned short* __restrict__ Vf)
{
    __shared__ unsigned short x_lds[64][264];
    const int tid = threadIdx.x;
    const int M0  = (blockIdx.x >> 1) * 64;
    const int ctb = (blockIdx.x & 1) * 10;

    #pragma unroll
    for (int j = 0; j < 16; ++j) {
        int idx = j * 256 + tid;
        int row = idx >> 6;
        int qc  = idx & 63;
        const float4 v = *reinterpret_cast<const float4*>(x + (size_t)(M0 + row) * 256 + qc * 4);
        ushort4 o;
        o.x = f2bf(v.x); o.y = f2bf(v.y); o.z = f2bf(v.z); o.w = f2bf(v.w);
        *reinterpret_cast<ushort4*>(&x_lds[row][qc * 4]) = o;
    }
    __syncthreads();

    const int w  = tid >> 6;
    const int l  = tid & 63;
    const int lr = l & 15;
    const int lg = l >> 4;

    short8 a[8];
    #pragma unroll
    for (int kk = 0; kk < 8; ++kk)
        a[kk] = *reinterpret_cast<const short8*>(&x_lds[w * 16 + lr][kk * 32 + lg * 8]);

    const int b   = M0 >> 12;          // batch
    const int kt  = (M0 & 4095) >> 6;  // 64-token tile within batch

    for (int ct = ctb; ct < ctb + 10; ++ct) {
        const int col = ct * 16 + lr;           // 0..319
        f32x4 acc = {0.f, 0.f, 0.f, 0.f};
        #pragma unroll
        for (int kk = 0; kk < 8; ++kk) {
            const short8 bfr = *reinterpret_cast<const short8*>(
                Wtf + ((size_t)ct * 8 + kk) * 512 + l * 8);
            acc = __builtin_amdgcn_mfma_f32_16x16x32_bf16(a[kk], bfr, acc, 0, 0, 0);
        }
        const int rbase = M0 + w * 16 + lg * 4;        // global token of reg 0
        if (ct < 2) {           // Q, pre-scaled by log2e
            const float bias = bq[col];
            #pragma unroll
            for (int r = 0; r < 4; ++r)
                Qb[(size_t)(rbase + r) * 32 + col] = f2bf((acc[r] + bias) * LOG2E);
        } else if (ct < 4) {    // K -> fragment layout
            const int colp = col - 32;
            const float bias = bk[colp];
            const int dd = colp >> 4, hj = (colp >> 3) & 1, jj = colp & 7;
            #pragma unroll
            for (int r = 0; r < 4; ++r) {
                const int tt = (rbase + r) & 4095;
                const size_t e = (size_t)b * 131072 + (size_t)kt * 2048
                               + (((tt >> 5) & 1) * 2 + dd) * 512
                               + (hj * 32 + (tt & 31)) * 8 + jj;
                Kf[e] = f2bf(acc[r] + bias);
            }
        } else {                // V -> fragment layout (one 8B write)
            const int colp = col - 64;
            const float bias = bv[colp];
            const int kk_f = w;
            const int hi_v = (lg >> 1) & 1;
            const int j0   = (lg & 1) * 4;
            const size_t e = (size_t)b * 1048576 + (size_t)kt * 16384
                           + (colp >> 5) * 2048 + kk_f * 512
                           + (hi_v * 32 + (colp & 31)) * 8 + j0;
            ushort4 o;
            o.x = f2bf(acc[0] + bias); o.y = f2bf(acc[1] + bias);
            o.z = f2bf(acc[2] + bias); o.w = f2bf(acc[3] + bias);
            *reinterpret_cast<ushort4*>(Vf + e) = o;
        }
    }
}

// ---------------------------------------------------------------------------
// Kernel 2: flash attention — r17 VERBATIM (best measured: 58.1 µs).
// Register softmax, fragment-linear K/V loads, cross-body V + kA double-
// buffers, ILP-shaped (PV kk-outer, QK interleaved, 4 rowsum chains),
// VALU rowsum, NO setprio (r12: -25%), NO LDS staging (r18: -64%).
// Grid 1024 x 128 (2 independent kh waves).
// ---------------------------------------------------------------------------
__global__ __launch_bounds__(128, 2) void attn_kernel(
    const unsigned short* __restrict__ Qb, const unsigned short* __restrict__ Kf,
    const unsigned short* __restrict__ Vf, const float* __restrict__ x,
    const float* __restrict__ gamma_p, float* __restrict__ out)
{
    __shared__ float O_sh[4][16][64];   // partner partials, 16KB
    __shared__ float l_sh[2][32];

    const int i  = blockIdx.x;
    const int b  = (i & 7) >> 1;                    // batch -> XCD pair
    const int t  = ((i >> 3) << 1) | (i & 1);       // 0..255
    const int qt = t >> 1;                          // 0..127
    const int cg = t & 1;                           // col half

    const int tid = threadIdx.x;
    const int kh  = tid >> 6;                       // K-half wave
    const int l   = tid & 63;
    const int l5  = l & 31;
    const int hi  = l >> 5;

    const size_t bN = (size_t)b * 4096;
    const int q0 = qt * 32;
    const int c0 = cg * 128;

    // fragment bases (lane offset folded in)
    const unsigned short* Kfb = Kf + (size_t)b * 131072 + l * 8;
    const unsigned short* Vfb = Vf + (size_t)b * 1048576 + (c0 >> 5) * 2048 + l * 8;

    // Q B-frags (pre-scaled by log2e in proj)
    short8 qb[2];
    #pragma unroll
    for (int dd = 0; dd < 2; ++dd)
        qb[dd] = *reinterpret_cast<const short8*>(
            Qb + (bN + (size_t)(q0 + l5)) * 32 + dd * 16 + hi * 8);

    f32x16 Oa[4];
    #pragma unroll
    for (int ct = 0; ct < 4; ++ct)
        #pragma unroll
        for (int r = 0; r < 16; ++r) Oa[ct][r] = 0.f;
    float ls0 = 0.f, ls1 = 0.f, ls2 = 0.f, ls3 = 0.f;   // 4 chains of 8/body

    f32x16 z;
    #pragma unroll
    for (int r = 0; r < 16; ++r) z[r] = 0.f;

    const int kt0 = kh * 32;                        // wave's first 64-token tile

    auto loadK = [&](short8 (&kA)[2][2], int ktg) {
        const unsigned short* kp = Kfb + (size_t)ktg * 2048;
        #pragma unroll
        for (int ks = 0; ks < 2; ++ks)
            #pragma unroll
            for (int dd = 0; dd < 2; ++dd)
                kA[ks][dd] = *reinterpret_cast<const short8*>(kp + (ks * 2 + dd) * 512);
    };
    auto loadV = [&](short8 (&vA)[4][4], int ktg) {
        const unsigned short* vp = Vfb + (size_t)ktg * 16384;
        #pragma unroll
        for (int ct = 0; ct < 4; ++ct)
            #pragma unroll
            for (int kk = 0; kk < 4; ++kk)
                vA[ct][kk] = *reinterpret_cast<const short8*>(vp + ct * 2048 + kk * 512);
    };

    // body: prefetch NEXT body's V and K first; compute with current buffers.
    auto body = [&](short8 (&kcur)[2][2], short8 (&knxt)[2][2],
                    short8 (&vcur)[4][4], short8 (&vnxt)[4][4], int ktgn) {
        loadV(vnxt, ktgn);                          // full-body latency cover
        loadK(knxt, ktgn);
        // swapped QK^T, p0/p1 interleaved (independent chains, distance 2)
        f32x16 p0 = __builtin_amdgcn_mfma_f32_32x32x16_bf16(kcur[0][0], qb[0], z, 0, 0, 0);
        f32x16 p1 = __builtin_amdgcn_mfma_f32_32x32x16_bf16(kcur[1][0], qb[0], z, 0, 0, 0);
        p0        = __builtin_amdgcn_mfma_f32_32x32x16_bf16(kcur[0][1], qb[1], p0, 0, 0, 0);
        p1        = __builtin_amdgcn_mfma_f32_32x32x16_bf16(kcur[1][1], qb[1], p1, 0, 0, 0);
        // exp2 + rowsum (4 chains) + pack + permlane -> PV A-frags
        short8 pa[4];
        #pragma unroll
        for (int ks = 0; ks < 2; ++ks) {
            float e[16];
            #pragma unroll
            for (int r = 0; r < 16; ++r) {
                const float s = (ks == 0) ? p0[r] : p1[r];
                e[r] = exp2_hw(s);
                switch (r & 3) {
                    case 0: ls0 += e[r]; break;
                    case 1: ls1 += e[r]; break;
                    case 2: ls2 += e[r]; break;
                    default: ls3 += e[r]; break;
                }
            }
            unsigned c[8];
            #pragma unroll
            for (int n = 0; n < 8; ++n) c[n] = cvt_pk_bf16(e[2 * n], e[2 * n + 1]);
            #pragma unroll
            for (int k2 = 0; k2 < 2; ++k2) {
                unsigned d0 = c[4 * k2 + 0], d2 = c[4 * k2 + 2];
                unsigned d1 = c[4 * k2 + 1], d3 = c[4 * k2 + 3];
                asm("v_permlane32_swap_b32 %0, %1" : "+v"(d0), "+v"(d2));
                asm("v_permlane32_swap_b32 %0, %1" : "+v"(d1), "+v"(d3));
                u32x4 u = {d0, d1, d2, d3};
                pa[ks * 2 + k2] = __builtin_bit_cast(short8, u);
            }
        }
        // PV: kk-outer -> same-accumulator MFMAs are 4 apart (indep chains)
        #pragma unroll
        for (int kk = 0; kk < 4; ++kk)
            #pragma unroll
            for (int ct = 0; ct < 4; ++ct)
                Oa[ct] = __builtin_amdgcn_mfma_f32_32x32x16_bf16(pa[kk], vcur[ct][kk], Oa[ct], 0, 0, 0);
    };

    short8 kA0[2][2], kA1[2][2];
    short8 vA[4][4], vB[4][4];
    loadK(kA0, kt0);
    loadV(vA, kt0);
    for (int kt = 0; kt < 32; kt += 2) {
        body(kA0, kA1, vA, vB, kt0 + kt + 1);
        body(kA1, kA0, vB, vA, kt0 + ((kt + 2) & 31));   // last prefetch wraps
    }

    // ---- combine: rowsum across hi halves; partner O partials via LDS ----
    float lsum = (ls0 + ls1) + (ls2 + ls3);
    lsum += __shfl_xor(lsum, 32);
    if (hi == 0) l_sh[kh][l5] = lsum;
    #pragma unroll
    for (int ct = 0; ct < 4; ++ct)
        if ((ct >> 1) != kh) {
            #pragma unroll
            for (int r = 0; r < 16; ++r)
                O_sh[ct][r][hi * 32 + l5] = Oa[ct][r];
        }
    __syncthreads();

    const float gamma = gamma_p[0];
    #pragma unroll
    for (int ct = 0; ct < 4; ++ct)
        if ((ct >> 1) == kh) {
            #pragma unroll
            for (int r = 0; r < 16; ++r) {
                const int qr = (r & 3) + 8 * (r >> 2) + 4 * hi;
                const float ltot = l_sh[0][qr] + l_sh[1][qr];
                const float osum = Oa[ct][r] + O_sh[ct][r][hi * 32 + l5];
                const size_t idx = (bN + (size_t)(q0 + qr)) * 256 + c0 + ct * 32 + l5;
                out[idx] = gamma * (osum / ltot) + x[idx];
            }
        }
}

// ---------------------------------------------------------------------------
extern "C" void kernel_launch(void* const* d_in, const int* in_sizes, int n_in,
                              void* d_out, int out_size, void* d_ws, size_t ws_size,
                              hipStream_t stream) {
    const float* x     = (const float*)d_in[0];
    const float* Wq    = (const float*)d_in[1];
    const float* bq    = (const float*)d_in[2];
    const float* Wk    = (const float*)d_in[3];
    const float* bk    = (const float*)d_in[4];
    const float* Wv    = (const float*)d_in[5];
    const float* bv    = (const float*)d_in[6];
    const float* gamma = (const float*)d_in[7];
    float* out = (float*)d_out;

    // workspace: Qb 1MB | Kf 1MB | Vf 8MB | Wtf 160KB (bf16)
    unsigned short* Qb  = (unsigned short*)d_ws;
    unsigned short* Kf  = Qb + (size_t)16384 * 32;
    unsigned short* Vf  = Kf + (size_t)16384 * 32;
    unsigned short* Wtf = Vf + (size_t)4 * 256 * 4096;

    transpose_w<<<160, 64, 0, stream>>>(Wq, Wk, Wv, Wtf);
    proj_kernel<<<512, 256, 0, stream>>>(x, Wtf, bq, bk, bv, Qb, Kf, Vf);
    attn_kernel<<<1024, 128, 0, stream>>>(Qb, Kf, Vf, x, gamma, out);
}